// Round 11
// baseline (45.889 us; speedup 1.0000x reference)
//
#include <hip/hip_runtime.h>

#define B_ 4096
#define C_ 128
#define EPS_ATT 1e-9f
#define EPS_BN 1e-5f
#define LOG2E 1.44269504088896f
#define GRID_KB 1024
#define NPB 4  // batches per persistent block (4096 / 1024)

using short8 = __attribute__((ext_vector_type(8))) short;
using f32x4 = __attribute__((ext_vector_type(4))) float;
using us4 = __attribute__((ext_vector_type(4))) unsigned short;
using u32x2 = __attribute__((ext_vector_type(2))) unsigned int;

__device__ __forceinline__ unsigned short bf16b(float x) {
    __bf16 h = (__bf16)x;
    return __builtin_bit_cast(unsigned short, h);
}

// ---------------------------------------------------------------------------
// Kernel 1 (R11): persistent k_batch. Grid 1024 (= 4 blocks/CU, the same
// occupancy R7 already ran at); each block processes batches
// b, b+1024, b+2048, b+3072. Next batch's x1/x2/x12 are PREFETCHED right
// after B0, hiding the ~600-900cy global latency under the current
// iteration's compute (R8 showed one exposed load/block costs ~4us across
// the pipeline). Batch-invariant fcw staging hoisted out of the loop.
// All six compute phases are R7-EXACT; no new barriers (cross-iteration
// hazards ordered by B0 — audit in round notes).
__global__ __launch_bounds__(256, 4) void k_batch(
    const float* __restrict__ x1, const float* __restrict__ x2,
    const float* __restrict__ x12,
    const float* __restrict__ fcw, const float* __restrict__ fcb,
    float* __restrict__ XR, float* __restrict__ GX1) {
    const int tid = threadIdx.x;
    const int lane = tid & 63;
    const int w = tid >> 6;     // wave 0..3
    const int g = lane >> 4;    // k-group 0..3
    const int ls = lane & 15;   // sixteen-index

    __shared__ char s_buf[C_ * C_ * 2] __attribute__((aligned(16)));
    __shared__ float s_x1[C_] __attribute__((aligned(16)));
    __shared__ float s_x2[C_] __attribute__((aligned(16)));
    __shared__ float s_fcC[C_] __attribute__((aligned(16)));
    __shared__ float s_invZ[C_] __attribute__((aligned(16)));
    __shared__ float s_cs4[4][C_] __attribute__((aligned(16)));
    __shared__ float s_s24[4][C_] __attribute__((aligned(16)));
    __shared__ unsigned short s_f1bf[C_] __attribute__((aligned(16)));

    float* s_S1 = (float*)s_buf;
    float* s_xrr = (float*)(s_buf + 512);
    unsigned short* s_w3bf = (unsigned short*)(s_buf + 1024);

    // ---- batch-invariant staging (once per persistent block)
    if (tid < C_) {
        s_f1bf[tid] = bf16b(fcw[tid]);
        s_fcC[tid] = fcw[C_ + tid];
    }
    const float fc2C = fcw[2 * C_];
    const float fcb0 = fcb[0];

    // ---- initial prefetch (batch = blockIdx.x)
    int b = blockIdx.x;
    float pv1 = 0.f, pv2 = 0.f, pv12 = 0.f;
    if (tid < C_) {
        pv1 = x1[b * C_ + tid];
        pv2 = x2[b * C_ + tid];
        pv12 = x12[b * C_ + tid];
    }

    for (int it = 0; it < NPB; ++it, b += GRID_KB) {
        float v12 = 0.f;
        if (tid < C_) {
            s_x1[tid] = pv1;
            s_x2[tid] = pv2;
            v12 = pv12;
        }
        __syncthreads();  // B0

        // prefetch next batch — latency hidden under P1..P2 compute
        if (it + 1 < NPB && tid < C_) {
            pv1 = x1[(b + GRID_KB) * C_ + tid];
            pv2 = x2[(b + GRID_KB) * C_ + tid];
            pv12 = x12[(b + GRID_KB) * C_ + tid];
        }

        // ---- P1 (R7-exact): e-frags in regs + bf16 e staged swizzled; Z.
        short8 ef0[4], ef1[4];
        float zp0 = 0.f, zp1 = 0.f;
        {
            const float r0 = s_x1[32 * w + ls] * LOG2E;
            const float r1 = s_x1[32 * w + 16 + ls] * LOG2E;
            char* erow0 = s_buf + (32 * w + ls) * 256;
            char* erow1 = s_buf + (32 * w + 16 + ls) * 256;
            const int sw = (ls & 7) << 4;
#pragma unroll
            for (int q = 0; q < 4; ++q) {
                f32x4 xa = *(const f32x4*)&s_x2[32 * q + 8 * g];
                f32x4 xb = *(const f32x4*)&s_x2[32 * q + 8 * g + 4];
                union {
                    short8 v;
                    unsigned short u[8];
                } p0, p1;
#pragma unroll
                for (int j = 0; j < 4; ++j) {
                    float a0 = __builtin_amdgcn_exp2f(r0 * xa[j]);
                    float b0 = __builtin_amdgcn_exp2f(r0 * xb[j]);
                    float a1 = __builtin_amdgcn_exp2f(r1 * xa[j]);
                    float b1 = __builtin_amdgcn_exp2f(r1 * xb[j]);
                    zp0 += a0 + b0;
                    zp1 += a1 + b1;
                    p0.u[j] = bf16b(a0);
                    p0.u[j + 4] = bf16b(b0);
                    p1.u[j] = bf16b(a1);
                    p1.u[j + 4] = bf16b(b1);
                }
                ef0[q] = p0.v;
                ef1[q] = p1.v;
                const int off = (64 * q + 16 * g) ^ sw;
                *(short8*)(erow0 + off) = p0.v;
                *(short8*)(erow1 + off) = p1.v;
            }
        }
        zp0 += __shfl_xor(zp0, 16);
        zp0 += __shfl_xor(zp0, 32);
        zp1 += __shfl_xor(zp1, 16);
        zp1 += __shfl_xor(zp1, 32);
        if (lane < 16) {
            s_invZ[32 * w + ls] = 1.f / zp0;
            s_invZ[32 * w + 16 + ls] = 1.f / zp1;
        }
        __syncthreads();  // B1

        // ---- P2 (R7-exact): colsum/S2 wave partials from staged bf16 e.
        {
            const int grp = tid & 31;
            const int sl = tid >> 5;
            const char* eb = s_buf + sl * 16 * 256;
            const int octb = grp >> 1;
            const int hoff = (grp & 1) * 8;
            float cs[4] = {0.f, 0.f, 0.f, 0.f};
            float s2[4] = {0.f, 0.f, 0.f, 0.f};
#pragma unroll
            for (int k = 0; k < 4; ++k) {
                f32x4 iz4 = *(const f32x4*)&s_invZ[sl * 16 + 4 * k];
                f32x4 fc4 = *(const f32x4*)&s_fcC[sl * 16 + 4 * k];
#pragma unroll
                for (int rr = 0; rr < 4; ++rr) {
                    const int r = 4 * k + rr;
                    const float iz = iz4[rr];
                    const float izf = iz * fc4[rr];
                    u32x2 ev = *(const u32x2*)(eb + r * 256 +
                                               ((octb ^ (r & 7)) << 4) + hoff);
#pragma unroll
                    for (int d = 0; d < 2; ++d) {
                        float elo = __builtin_bit_cast(float, ev[d] << 16);
                        float ehi =
                            __builtin_bit_cast(float, ev[d] & 0xffff0000u);
                        cs[2 * d] = fmaf(elo, iz, cs[2 * d]);
                        s2[2 * d] = fmaf(elo, izf, s2[2 * d]);
                        cs[2 * d + 1] = fmaf(ehi, iz, cs[2 * d + 1]);
                        s2[2 * d + 1] = fmaf(ehi, izf, s2[2 * d + 1]);
                    }
                }
            }
#pragma unroll
            for (int k = 0; k < 4; ++k) {
                cs[k] += __shfl_xor(cs[k], 32);
                s2[k] += __shfl_xor(s2[k], 32);
            }
            if ((sl & 1) == 0) {
                f32x4 c4 = {cs[0], cs[1], cs[2], cs[3]};
                f32x4 t4 = {s2[0], s2[1], s2[2], s2[3]};
                *(f32x4*)&s_cs4[w][grp * 4] = c4;
                *(f32x4*)&s_s24[w][grp * 4] = t4;
            }
        }
        __syncthreads();  // B2

        if (tid < C_) {
            float cs = s_cs4[0][tid] + s_cs4[1][tid] + s_cs4[2][tid] +
                       s_cs4[3][tid];
            float w3 = v12 / (EPS_ATT + cs);
            s_w3bf[tid] = bf16b(w3);
        }
        __syncthreads();  // B3

        // ---- MFMA-xr (R7-exact).
        {
            const short8 z8 = {0, 0, 0, 0, 0, 0, 0, 0};
            short8 bq[4];
#pragma unroll
            for (int q = 0; q < 4; ++q) {
                if (ls == 0)
                    bq[q] = *(const short8*)&s_f1bf[q * 32 + g * 8];
                else if (ls == 1)
                    bq[q] = *(const short8*)&s_w3bf[q * 32 + g * 8];
                else
                    bq[q] = z8;
            }
            f32x4 acc0 = {0.f, 0.f, 0.f, 0.f};
            f32x4 acc1 = {0.f, 0.f, 0.f, 0.f};
#pragma unroll
            for (int q = 0; q < 4; ++q) {
                acc0 = __builtin_amdgcn_mfma_f32_16x16x32_bf16(ef0[q], bq[q], acc0, 0, 0, 0);
                acc1 = __builtin_amdgcn_mfma_f32_16x16x32_bf16(ef1[q], bq[q], acc1, 0, 0, 0);
            }
            if (ls < 2) {
                float* dst = ls ? s_xrr : s_S1;
                *(f32x4*)&dst[(2 * w + 0) * 16 + g * 4] = acc0;
                *(f32x4*)&dst[(2 * w + 1) * 16 + g * 4] = acc1;
            }
        }
        __syncthreads();  // B4

        // ---- finalize (R7-exact numerics).
        if (tid < C_) {
            float invz = s_invZ[tid];
            float S1 = s_S1[tid] * invz;
            float xr = s_xrr[tid] * invz;
            float S2 = s_s24[0][tid] + s_s24[1][tid] + s_s24[2][tid] +
                       s_s24[3][tid];
            XR[b * C_ + tid] = xr;
            float gg = S1 + S2 + s_x1[tid] * fc2C + fcb0;
            float gate = 1.f / (1.f + __builtin_amdgcn_exp2f(-LOG2E * gg));
            GX1[b * C_ + tid] = gate * s_x1[tid];
        }
    }
}

// ---------------------------------------------------------------------------
// Kernel 2: MFMA conv (R7/R10-EXACT, verified). Grid 256 x 512 threads.
__global__ __launch_bounds__(512) void k_conv(
    const float* __restrict__ W, const float* __restrict__ XR,
    const float* __restrict__ x1, const float* __restrict__ convb,
    float* __restrict__ Y, float* __restrict__ pst) {
    const int blk = blockIdx.x;  // 0..255
    const int tid = threadIdx.x;
    const int bb = blk * 16;
    const int lane = tid & 63;
    const int wid = tid >> 6;   // wave 0..7
    const int g = lane >> 4;
    const int ls = lane & 15;

    __shared__ unsigned short s_Wb[C_ * C_] __attribute__((aligned(16)));  // 32KB
    __shared__ unsigned short s_xrb[16 * 136] __attribute__((aligned(16)));

    {
        const int r = tid >> 2;
        const int c0 = (tid & 3) * 4;
        const float* src = W + r * C_ + c0 * 8;
#pragma unroll
        for (int c = 0; c < 4; ++c) {
            f32x4 a = *(const f32x4*)(src + c * 8);
            f32x4 b2 = *(const f32x4*)(src + c * 8 + 4);
            union {
                short8 v;
                unsigned short u[8];
            } p;
#pragma unroll
            for (int j = 0; j < 4; ++j) {
                p.u[j] = bf16b(a[j]);
                p.u[j + 4] = bf16b(b2[j]);
            }
            *(short8*)&s_Wb[r * C_ + (((c0 + c) ^ (r & 7)) << 3)] = p.v;
        }
    }
    {
        const int r = tid >> 5;
        const int c = (tid & 31) * 4;
        f32x4 a = *(const f32x4*)&XR[(bb + r) * C_ + c];
        us4 p;
#pragma unroll
        for (int j = 0; j < 4; ++j) p[j] = bf16b(a[j]);
        *(us4*)&s_xrb[r * 136 + c] = p;
    }
    __syncthreads();

    {
        const int n = 16 * wid + ls;
        short8 aq[4], bq[4];
#pragma unroll
        for (int q = 0; q < 4; ++q) {
            aq[q] = *(const short8*)&s_xrb[ls * 136 + 32 * q + 8 * g];
            bq[q] = *(const short8*)&s_Wb[n * C_ + (((4 * q + g) ^ (n & 7)) << 3)];
        }
        f32x4 acc = {0.f, 0.f, 0.f, 0.f};
#pragma unroll
        for (int q = 0; q < 4; ++q)
            acc = __builtin_amdgcn_mfma_f32_16x16x32_bf16(aq[q], bq[q], acc, 0, 0, 0);

        const float cbv = convb[n];
        float ps = 0.f, pq = 0.f;
#pragma unroll
        for (int r = 0; r < 4; ++r) {
            const int m = 4 * g + r;
            float y = x1[(bb + m) * C_ + n] - (acc[r] + cbv);
            Y[(bb + m) * C_ + n] = y;
            ps += y;
            pq += y * y;
        }
        ps += __shfl_xor(ps, 16);
        ps += __shfl_xor(ps, 32);
        pq += __shfl_xor(pq, 16);
        pq += __shfl_xor(pq, 32);
        if (lane < 16) {
            pst[n * 256 + blk] = ps;
            pst[32768 + n * 256 + blk] = pq;
        }
    }
}

// ---------------------------------------------------------------------------
// Kernel 3: fold pst -> A/Bc once (R10-EXACT, verified).
__global__ __launch_bounds__(256) void k_fold(const float* __restrict__ pst,
                                              const float* __restrict__ gamma,
                                              const float* __restrict__ beta,
                                              float* __restrict__ AB) {
    const int ch = blockIdx.x;  // 0..127
    const int t = threadIdx.x;  // 0..255
    __shared__ float sh[256];
    __shared__ float sh2[256];
    sh[t] = pst[ch * 256 + t];
    sh2[t] = pst[32768 + ch * 256 + t];
    __syncthreads();
    for (int off = 128; off > 0; off >>= 1) {
        if (t < off) {
            sh[t] += sh[t + off];
            sh2[t] += sh2[t + off];
        }
        __syncthreads();
    }
    if (t == 0) {
        float mean = sh[0] / (float)B_;
        float var = sh2[0] / (float)B_ - mean * mean;
        float A = gamma[ch] * rsqrtf(var + EPS_BN);
        AB[ch] = A;
        AB[C_ + ch] = beta[ch] - mean * A;
    }
}

// ---------------------------------------------------------------------------
// Kernel 4: out += relu(Y*A + Bc), float4 (R10-EXACT, verified).
__global__ __launch_bounds__(256) void k_final(const float* __restrict__ Y,
                                               const float* __restrict__ AB,
                                               float* __restrict__ out) {
    __shared__ float sA[C_];
    __shared__ float sB[C_];
    const int t = threadIdx.x;
    if (t < C_) {
        sA[t] = AB[t];
        sB[t] = AB[C_ + t];
    }
    __syncthreads();
    const int i4 = blockIdx.x * 256 + t;  // float4 index; grid covers exactly
    float4 y = ((const float4*)Y)[i4];
    float4 o = ((const float4*)out)[i4];
    const int ch = (i4 * 4) & (C_ - 1);
    o.x += fmaxf(y.x * sA[ch + 0] + sB[ch + 0], 0.f);
    o.y += fmaxf(y.y * sA[ch + 1] + sB[ch + 1], 0.f);
    o.z += fmaxf(y.z * sA[ch + 2] + sB[ch + 2], 0.f);
    o.w += fmaxf(y.w * sA[ch + 3] + sB[ch + 3], 0.f);
    ((float4*)out)[i4] = o;
}

// ---------------------------------------------------------------------------
extern "C" void kernel_launch(void* const* d_in, const int* in_sizes, int n_in,
                              void* d_out, int out_size, void* d_ws,
                              size_t ws_size, hipStream_t stream) {
    const float* x1 = (const float*)d_in[0];
    const float* x2 = (const float*)d_in[1];
    const float* x12 = (const float*)d_in[2];
    const float* convw = (const float*)d_in[3];
    const float* convb = (const float*)d_in[4];
    const float* gamma = (const float*)d_in[5];
    const float* beta = (const float*)d_in[6];
    const float* fcw = (const float*)d_in[7];
    const float* fcb = (const float*)d_in[8];
    float* out = (float*)d_out;

    float* XR = (float*)d_ws;               // B*C
    float* Y = XR + (size_t)B_ * C_;        // B*C
    float* pst = Y + (size_t)B_ * C_;       // 2*C*256
    float* AB = pst + 2 * C_ * 256;         // 2*C

    k_batch<<<GRID_KB, 256, 0, stream>>>(x1, x2, x12, fcw, fcb, XR, out);
    k_conv<<<256, 512, 0, stream>>>(convw, XR, x1, convb, Y, pst);
    k_fold<<<C_, 256, 0, stream>>>(pst, gamma, beta, AB);
    k_final<<<(B_ * C_ / 4) / 256, 256, 0, stream>>>(Y, AB, out);
}

// Round 12
// 35.046 us; speedup vs baseline: 1.3094x; 1.3094x over previous
//
#include <hip/hip_runtime.h>

#define B_ 4096
#define C_ 128
#define EPS_ATT 1e-9f
#define EPS_BN 1e-5f
#define LOG2E 1.44269504088896f

using short8 = __attribute__((ext_vector_type(8))) short;
using f32x4 = __attribute__((ext_vector_type(4))) float;
using us4 = __attribute__((ext_vector_type(4))) unsigned short;
using u32x2 = __attribute__((ext_vector_type(2))) unsigned int;

__device__ __forceinline__ unsigned short bf16b(float x) {
    __bf16 h = (__bf16)x;
    return __builtin_bit_cast(unsigned short, h);
}

// ---------------------------------------------------------------------------
// Kernel 1: one batch per block, 256 threads (4 waves). R7/R10-EXACT
// (verified 35.43us total). R11's persistent variant reverted: loop-top
// barriers force vmcnt(0) drains of finalize stores, persistent blocks
// lose start-staggering, and exact-capacity grids have no imbalance
// self-correction (R11: 45.9us).
__global__ __launch_bounds__(256, 4) void k_batch(
    const float* __restrict__ x1, const float* __restrict__ x2,
    const float* __restrict__ x12,
    const float* __restrict__ fcw, const float* __restrict__ fcb,
    float* __restrict__ XR, float* __restrict__ GX1) {
    const int b = blockIdx.x;
    const int tid = threadIdx.x;
    const int lane = tid & 63;
    const int w = tid >> 6;     // wave 0..3
    const int g = lane >> 4;    // k-group 0..3
    const int ls = lane & 15;   // sixteen-index

    __shared__ char s_buf[C_ * C_ * 2] __attribute__((aligned(16)));
    __shared__ float s_x1[C_] __attribute__((aligned(16)));
    __shared__ float s_x2[C_] __attribute__((aligned(16)));
    __shared__ float s_fcC[C_] __attribute__((aligned(16)));
    __shared__ float s_invZ[C_] __attribute__((aligned(16)));
    __shared__ float s_cs4[4][C_] __attribute__((aligned(16)));
    __shared__ float s_s24[4][C_] __attribute__((aligned(16)));
    __shared__ unsigned short s_f1bf[C_] __attribute__((aligned(16)));

    float* s_S1 = (float*)s_buf;
    float* s_xrr = (float*)(s_buf + 512);
    unsigned short* s_w3bf = (unsigned short*)(s_buf + 1024);

    float v12 = 0.f;
    if (tid < C_) {
        s_x1[tid] = x1[b * C_ + tid];
        s_x2[tid] = x2[b * C_ + tid];
        s_f1bf[tid] = bf16b(fcw[tid]);
        s_fcC[tid] = fcw[C_ + tid];
        v12 = x12[b * C_ + tid];
    }
    __syncthreads();  // B0

    short8 ef0[4], ef1[4];
    float zp0 = 0.f, zp1 = 0.f;
    {
        const float r0 = s_x1[32 * w + ls] * LOG2E;
        const float r1 = s_x1[32 * w + 16 + ls] * LOG2E;
        char* erow0 = s_buf + (32 * w + ls) * 256;
        char* erow1 = s_buf + (32 * w + 16 + ls) * 256;
        const int sw = (ls & 7) << 4;
#pragma unroll
        for (int q = 0; q < 4; ++q) {
            f32x4 xa = *(const f32x4*)&s_x2[32 * q + 8 * g];
            f32x4 xb = *(const f32x4*)&s_x2[32 * q + 8 * g + 4];
            union {
                short8 v;
                unsigned short u[8];
            } p0, p1;
#pragma unroll
            for (int j = 0; j < 4; ++j) {
                float a0 = __builtin_amdgcn_exp2f(r0 * xa[j]);
                float b0 = __builtin_amdgcn_exp2f(r0 * xb[j]);
                float a1 = __builtin_amdgcn_exp2f(r1 * xa[j]);
                float b1 = __builtin_amdgcn_exp2f(r1 * xb[j]);
                zp0 += a0 + b0;
                zp1 += a1 + b1;
                p0.u[j] = bf16b(a0);
                p0.u[j + 4] = bf16b(b0);
                p1.u[j] = bf16b(a1);
                p1.u[j + 4] = bf16b(b1);
            }
            ef0[q] = p0.v;
            ef1[q] = p1.v;
            const int off = (64 * q + 16 * g) ^ sw;
            *(short8*)(erow0 + off) = p0.v;
            *(short8*)(erow1 + off) = p1.v;
        }
    }
    zp0 += __shfl_xor(zp0, 16);
    zp0 += __shfl_xor(zp0, 32);
    zp1 += __shfl_xor(zp1, 16);
    zp1 += __shfl_xor(zp1, 32);
    if (lane < 16) {
        s_invZ[32 * w + ls] = 1.f / zp0;
        s_invZ[32 * w + 16 + ls] = 1.f / zp1;
    }
    __syncthreads();  // B1

    {
        const int grp = tid & 31;
        const int sl = tid >> 5;
        const char* eb = s_buf + sl * 16 * 256;
        const int octb = grp >> 1;
        const int hoff = (grp & 1) * 8;
        float cs[4] = {0.f, 0.f, 0.f, 0.f};
        float s2[4] = {0.f, 0.f, 0.f, 0.f};
#pragma unroll
        for (int k = 0; k < 4; ++k) {
            f32x4 iz4 = *(const f32x4*)&s_invZ[sl * 16 + 4 * k];
            f32x4 fc4 = *(const f32x4*)&s_fcC[sl * 16 + 4 * k];
#pragma unroll
            for (int rr = 0; rr < 4; ++rr) {
                const int r = 4 * k + rr;
                const float iz = iz4[rr];
                const float izf = iz * fc4[rr];
                u32x2 ev = *(const u32x2*)(eb + r * 256 +
                                           ((octb ^ (r & 7)) << 4) + hoff);
#pragma unroll
                for (int d = 0; d < 2; ++d) {
                    float elo = __builtin_bit_cast(float, ev[d] << 16);
                    float ehi =
                        __builtin_bit_cast(float, ev[d] & 0xffff0000u);
                    cs[2 * d] = fmaf(elo, iz, cs[2 * d]);
                    s2[2 * d] = fmaf(elo, izf, s2[2 * d]);
                    cs[2 * d + 1] = fmaf(ehi, iz, cs[2 * d + 1]);
                    s2[2 * d + 1] = fmaf(ehi, izf, s2[2 * d + 1]);
                }
            }
        }
#pragma unroll
        for (int k = 0; k < 4; ++k) {
            cs[k] += __shfl_xor(cs[k], 32);
            s2[k] += __shfl_xor(s2[k], 32);
        }
        if ((sl & 1) == 0) {
            f32x4 c4 = {cs[0], cs[1], cs[2], cs[3]};
            f32x4 t4 = {s2[0], s2[1], s2[2], s2[3]};
            *(f32x4*)&s_cs4[w][grp * 4] = c4;
            *(f32x4*)&s_s24[w][grp * 4] = t4;
        }
    }
    __syncthreads();  // B2

    if (tid < C_) {
        float cs = s_cs4[0][tid] + s_cs4[1][tid] + s_cs4[2][tid] + s_cs4[3][tid];
        float w3 = v12 / (EPS_ATT + cs);
        s_w3bf[tid] = bf16b(w3);
    }
    __syncthreads();  // B3

    {
        const short8 z8 = {0, 0, 0, 0, 0, 0, 0, 0};
        short8 bq[4];
#pragma unroll
        for (int q = 0; q < 4; ++q) {
            if (ls == 0)
                bq[q] = *(const short8*)&s_f1bf[q * 32 + g * 8];
            else if (ls == 1)
                bq[q] = *(const short8*)&s_w3bf[q * 32 + g * 8];
            else
                bq[q] = z8;
        }
        f32x4 acc0 = {0.f, 0.f, 0.f, 0.f};
        f32x4 acc1 = {0.f, 0.f, 0.f, 0.f};
#pragma unroll
        for (int q = 0; q < 4; ++q) {
            acc0 = __builtin_amdgcn_mfma_f32_16x16x32_bf16(ef0[q], bq[q], acc0, 0, 0, 0);
            acc1 = __builtin_amdgcn_mfma_f32_16x16x32_bf16(ef1[q], bq[q], acc1, 0, 0, 0);
        }
        if (ls < 2) {
            float* dst = ls ? s_xrr : s_S1;
            *(f32x4*)&dst[(2 * w + 0) * 16 + g * 4] = acc0;
            *(f32x4*)&dst[(2 * w + 1) * 16 + g * 4] = acc1;
        }
    }
    __syncthreads();  // B4

    if (tid < C_) {
        float invz = s_invZ[tid];
        float S1 = s_S1[tid] * invz;
        float xr = s_xrr[tid] * invz;
        float S2 = s_s24[0][tid] + s_s24[1][tid] + s_s24[2][tid] + s_s24[3][tid];
        XR[b * C_ + tid] = xr;
        float gg = S1 + S2 + s_x1[tid] * fcw[2 * C_] + fcb[0];
        float gate = 1.f / (1.f + __builtin_amdgcn_exp2f(-LOG2E * gg));
        GX1[b * C_ + tid] = gate * s_x1[tid];
    }
}

// ---------------------------------------------------------------------------
// Kernel 2: MFMA conv (R7/R10-EXACT, verified). Grid 256 x 512 threads.
__global__ __launch_bounds__(512) void k_conv(
    const float* __restrict__ W, const float* __restrict__ XR,
    const float* __restrict__ x1, const float* __restrict__ convb,
    float* __restrict__ Y, float* __restrict__ pst) {
    const int blk = blockIdx.x;  // 0..255
    const int tid = threadIdx.x;
    const int bb = blk * 16;
    const int lane = tid & 63;
    const int wid = tid >> 6;   // wave 0..7
    const int g = lane >> 4;
    const int ls = lane & 15;

    __shared__ unsigned short s_Wb[C_ * C_] __attribute__((aligned(16)));  // 32KB
    __shared__ unsigned short s_xrb[16 * 136] __attribute__((aligned(16)));

    {
        const int r = tid >> 2;
        const int c0 = (tid & 3) * 4;
        const float* src = W + r * C_ + c0 * 8;
#pragma unroll
        for (int c = 0; c < 4; ++c) {
            f32x4 a = *(const f32x4*)(src + c * 8);
            f32x4 b2 = *(const f32x4*)(src + c * 8 + 4);
            union {
                short8 v;
                unsigned short u[8];
            } p;
#pragma unroll
            for (int j = 0; j < 4; ++j) {
                p.u[j] = bf16b(a[j]);
                p.u[j + 4] = bf16b(b2[j]);
            }
            *(short8*)&s_Wb[r * C_ + (((c0 + c) ^ (r & 7)) << 3)] = p.v;
        }
    }
    {
        const int r = tid >> 5;
        const int c = (tid & 31) * 4;
        f32x4 a = *(const f32x4*)&XR[(bb + r) * C_ + c];
        us4 p;
#pragma unroll
        for (int j = 0; j < 4; ++j) p[j] = bf16b(a[j]);
        *(us4*)&s_xrb[r * 136 + c] = p;
    }
    __syncthreads();

    {
        const int n = 16 * wid + ls;
        short8 aq[4], bq[4];
#pragma unroll
        for (int q = 0; q < 4; ++q) {
            aq[q] = *(const short8*)&s_xrb[ls * 136 + 32 * q + 8 * g];
            bq[q] = *(const short8*)&s_Wb[n * C_ + (((4 * q + g) ^ (n & 7)) << 3)];
        }
        f32x4 acc = {0.f, 0.f, 0.f, 0.f};
#pragma unroll
        for (int q = 0; q < 4; ++q)
            acc = __builtin_amdgcn_mfma_f32_16x16x32_bf16(aq[q], bq[q], acc, 0, 0, 0);

        const float cbv = convb[n];
        float ps = 0.f, pq = 0.f;
#pragma unroll
        for (int r = 0; r < 4; ++r) {
            const int m = 4 * g + r;
            float y = x1[(bb + m) * C_ + n] - (acc[r] + cbv);
            Y[(bb + m) * C_ + n] = y;
            ps += y;
            pq += y * y;
        }
        ps += __shfl_xor(ps, 16);
        ps += __shfl_xor(ps, 32);
        pq += __shfl_xor(pq, 16);
        pq += __shfl_xor(pq, 32);
        if (lane < 16) {
            pst[n * 256 + blk] = ps;
            pst[32768 + n * 256 + blk] = pq;
        }
    }
}

// ---------------------------------------------------------------------------
// Kernel 3: fold pst -> A/Bc once (R10-EXACT, verified).
__global__ __launch_bounds__(256) void k_fold(const float* __restrict__ pst,
                                              const float* __restrict__ gamma,
                                              const float* __restrict__ beta,
                                              float* __restrict__ AB) {
    const int ch = blockIdx.x;  // 0..127
    const int t = threadIdx.x;  // 0..255
    __shared__ float sh[256];
    __shared__ float sh2[256];
    sh[t] = pst[ch * 256 + t];
    sh2[t] = pst[32768 + ch * 256 + t];
    __syncthreads();
    for (int off = 128; off > 0; off >>= 1) {
        if (t < off) {
            sh[t] += sh[t + off];
            sh2[t] += sh2[t + off];
        }
        __syncthreads();
    }
    if (t == 0) {
        float mean = sh[0] / (float)B_;
        float var = sh2[0] / (float)B_ - mean * mean;
        float A = gamma[ch] * rsqrtf(var + EPS_BN);
        AB[ch] = A;
        AB[C_ + ch] = beta[ch] - mean * A;
    }
}

// ---------------------------------------------------------------------------
// Kernel 4: out += relu(Y*A + Bc), float4 (R10-EXACT, verified).
__global__ __launch_bounds__(256) void k_final(const float* __restrict__ Y,
                                               const float* __restrict__ AB,
                                               float* __restrict__ out) {
    __shared__ float sA[C_];
    __shared__ float sB[C_];
    const int t = threadIdx.x;
    if (t < C_) {
        sA[t] = AB[t];
        sB[t] = AB[C_ + t];
    }
    __syncthreads();
    const int i4 = blockIdx.x * 256 + t;  // float4 index; grid covers exactly
    float4 y = ((const float4*)Y)[i4];
    float4 o = ((const float4*)out)[i4];
    const int ch = (i4 * 4) & (C_ - 1);
    o.x += fmaxf(y.x * sA[ch + 0] + sB[ch + 0], 0.f);
    o.y += fmaxf(y.y * sA[ch + 1] + sB[ch + 1], 0.f);
    o.z += fmaxf(y.z * sA[ch + 2] + sB[ch + 2], 0.f);
    o.w += fmaxf(y.w * sA[ch + 3] + sB[ch + 3], 0.f);
    ((float4*)out)[i4] = o;
}

// ---------------------------------------------------------------------------
extern "C" void kernel_launch(void* const* d_in, const int* in_sizes, int n_in,
                              void* d_out, int out_size, void* d_ws,
                              size_t ws_size, hipStream_t stream) {
    const float* x1 = (const float*)d_in[0];
    const float* x2 = (const float*)d_in[1];
    const float* x12 = (const float*)d_in[2];
    const float* convw = (const float*)d_in[3];
    const float* convb = (const float*)d_in[4];
    const float* gamma = (const float*)d_in[5];
    const float* beta = (const float*)d_in[6];
    const float* fcw = (const float*)d_in[7];
    const float* fcb = (const float*)d_in[8];
    float* out = (float*)d_out;

    float* XR = (float*)d_ws;               // B*C
    float* Y = XR + (size_t)B_ * C_;        // B*C
    float* pst = Y + (size_t)B_ * C_;       // 2*C*256
    float* AB = pst + 2 * C_ * 256;         // 2*C

    k_batch<<<B_, 256, 0, stream>>>(x1, x2, x12, fcw, fcb, XR, out);
    k_conv<<<256, 512, 0, stream>>>(convw, XR, x1, convb, Y, pst);
    k_fold<<<C_, 256, 0, stream>>>(pst, gamma, beta, AB);
    k_final<<<(B_ * C_ / 4) / 256, 256, 0, stream>>>(Y, AB, out);
}